// Round 1
// baseline (794.372 us; speedup 1.0000x reference)
//
#include <hip/hip_runtime.h>

#define HIDDEN 64
#define BETA 0.01f
#define GAMMA 0.01f

// ---------------------------------------------------------------------------
// Kernel 1: fused encode + projections, one wave per movie row.
//   h = features[m] @ W_enc + b_enc          (128 -> 64)
//   P[m] = h @ W_p ; Q[m] = h @ W_q          (64 -> 64)
//   also accumulates 0.5*BETA*sum(P^2+Q^2) into out_loss.
// Wave-local: feature row read via broadcast (uniform address) loads,
// h row shared across lanes via __shfl. No LDS, no barriers in the loop.
// ---------------------------------------------------------------------------
__global__ void encode_kernel(const float* __restrict__ features,
                              const float* __restrict__ W_enc,
                              const float* __restrict__ b_enc,
                              const float* __restrict__ W_p,
                              const float* __restrict__ W_q,
                              float* __restrict__ P,
                              float* __restrict__ Q,
                              float* __restrict__ out_loss,
                              int num_movies, int in_feats) {
    const int lane  = threadIdx.x & 63;
    const int gwave = (blockIdx.x * blockDim.x + threadIdx.x) >> 6;
    const int nwaves = (gridDim.x * blockDim.x) >> 6;

    const float be = b_enc[lane];
    float reg = 0.0f;

    for (int m = gwave; m < num_movies; m += nwaves) {
        const float* frow = features + (size_t)m * in_feats;
        float h = be;
        for (int f = 0; f < in_feats; ++f) {
            h = fmaf(frow[f], W_enc[f * HIDDEN + lane], h);
        }
        float p = 0.0f, q = 0.0f;
        #pragma unroll 8
        for (int j = 0; j < HIDDEN; ++j) {
            float hj = __shfl(h, j);
            p = fmaf(hj, W_p[j * HIDDEN + lane], p);
            q = fmaf(hj, W_q[j * HIDDEN + lane], q);
        }
        P[(size_t)m * HIDDEN + lane] = p;
        Q[(size_t)m * HIDDEN + lane] = q;
        reg += p * p + q * q;
    }

    // block reduction of reg, one atomic per block
    for (int off = 32; off; off >>= 1) reg += __shfl_down(reg, off);
    __shared__ float s_part[16];
    const int wave = threadIdx.x >> 6;
    if (lane == 0) s_part[wave] = reg;
    __syncthreads();
    if (threadIdx.x == 0) {
        float t = 0.0f;
        const int nw = blockDim.x >> 6;
        for (int w = 0; w < nw; ++w) t += s_part[w];
        atomicAdd(out_loss, 0.5f * BETA * t);
    }
}

// ---------------------------------------------------------------------------
// Kernel 2: sparse COO scatter:
//   user_emb[rows[e]] += vals[e] * P[cols[e]]   (64-wide, lane k = comp k)
//   user_deg[rows[e]] += vals[e]
// One 64-lane group per entry (grid-stride over entries).
// ---------------------------------------------------------------------------
__global__ void scatter_kernel(const float* __restrict__ vals,
                               const int* __restrict__ rows,
                               const int* __restrict__ cols,
                               const float* __restrict__ P,
                               float* __restrict__ user_emb,
                               float* __restrict__ user_deg,
                               int nnz) {
    const int gid  = blockIdx.x * blockDim.x + threadIdx.x;
    const int lane = gid & 63;
    const int group = gid >> 6;
    const int ngroups = (gridDim.x * blockDim.x) >> 6;

    for (int e = group; e < nnz; e += ngroups) {
        const int r = rows[e];
        const int c = cols[e];
        const float v = vals[e];
        atomicAdd(&user_emb[(size_t)r * HIDDEN + lane],
                  v * P[(size_t)c * HIDDEN + lane]);
        if (lane == 0) atomicAdd(&user_deg[r], v);
    }
}

// ---------------------------------------------------------------------------
// Kernel 3: pair loss. One thread per positive pair.
//   r_ui  = b_u[u] + b_i[i] + dot(user_emb[u]/deg[u], Q[i])
//   for s: neg = b_u[u] + b_i[j] + dot(ue, Q[j]); diff = 1-(r-neg)
//   loss += 0.5*diff^2
// ---------------------------------------------------------------------------
__global__ void loss_kernel(const float* __restrict__ user_emb,
                            const float* __restrict__ user_deg,
                            const float* __restrict__ Q,
                            const float* __restrict__ b_u,
                            const float* __restrict__ b_i,
                            const int* __restrict__ rows,
                            const int* __restrict__ cols,
                            const int* __restrict__ pos_idx,
                            const int* __restrict__ neg_item_idx,
                            int num_pos, int S,
                            float* __restrict__ out_loss) {
    const int p = blockIdx.x * blockDim.x + threadIdx.x;
    float acc = 0.0f;

    if (p < num_pos) {
        const int e = pos_idx[p];
        const int u = rows[e];
        const int ii = cols[e];
        const float invdeg = 1.0f / user_deg[u];

        float ue[HIDDEN];
        const float4* uep = (const float4*)(user_emb + (size_t)u * HIDDEN);
        #pragma unroll
        for (int k = 0; k < HIDDEN / 4; ++k) {
            float4 t4 = uep[k];
            ue[4 * k + 0] = t4.x * invdeg;
            ue[4 * k + 1] = t4.y * invdeg;
            ue[4 * k + 2] = t4.z * invdeg;
            ue[4 * k + 3] = t4.w * invdeg;
        }
        const float bu = b_u[u];

        const float4* qp = (const float4*)(Q + (size_t)ii * HIDDEN);
        float dot = 0.0f;
        #pragma unroll
        for (int k = 0; k < HIDDEN / 4; ++k) {
            float4 t4 = qp[k];
            dot = fmaf(ue[4 * k + 0], t4.x, dot);
            dot = fmaf(ue[4 * k + 1], t4.y, dot);
            dot = fmaf(ue[4 * k + 2], t4.z, dot);
            dot = fmaf(ue[4 * k + 3], t4.w, dot);
        }
        const float r = bu + b_i[ii] + dot;

        for (int s = 0; s < S; ++s) {
            const int j = neg_item_idx[(size_t)p * S + s];
            const float4* qn = (const float4*)(Q + (size_t)j * HIDDEN);
            float dn = 0.0f;
            #pragma unroll
            for (int k = 0; k < HIDDEN / 4; ++k) {
                float4 t4 = qn[k];
                dn = fmaf(ue[4 * k + 0], t4.x, dn);
                dn = fmaf(ue[4 * k + 1], t4.y, dn);
                dn = fmaf(ue[4 * k + 2], t4.z, dn);
                dn = fmaf(ue[4 * k + 3], t4.w, dn);
            }
            const float nr = bu + b_i[j] + dn;
            const float diff = 1.0f - (r - nr);
            acc += 0.5f * diff * diff;
        }
    }

    // block reduction, one atomic per block
    for (int off = 32; off; off >>= 1) acc += __shfl_down(acc, off);
    __shared__ float s_part[16];
    const int wave = threadIdx.x >> 6;
    const int lane = threadIdx.x & 63;
    if (lane == 0) s_part[wave] = acc;
    __syncthreads();
    if (threadIdx.x == 0) {
        float t = 0.0f;
        const int nw = blockDim.x >> 6;
        for (int w = 0; w < nw; ++w) t += s_part[w];
        atomicAdd(out_loss, t);
    }
}

// ---------------------------------------------------------------------------
// Kernel 4: bias regularizer 0.5*GAMMA*(sum b_u^2 + sum b_i^2)
// ---------------------------------------------------------------------------
__global__ void bias_reg_kernel(const float* __restrict__ b_u, int nu,
                                const float* __restrict__ b_i, int ni,
                                float* __restrict__ out_loss) {
    const int tid = blockIdx.x * blockDim.x + threadIdx.x;
    const int stride = gridDim.x * blockDim.x;
    const int n = nu + ni;
    float acc = 0.0f;
    for (int x = tid; x < n; x += stride) {
        float v = (x < nu) ? b_u[x] : b_i[x - nu];
        acc += v * v;
    }
    for (int off = 32; off; off >>= 1) acc += __shfl_down(acc, off);
    __shared__ float s_part[16];
    const int wave = threadIdx.x >> 6;
    const int lane = threadIdx.x & 63;
    if (lane == 0) s_part[wave] = acc;
    __syncthreads();
    if (threadIdx.x == 0) {
        float t = 0.0f;
        const int nw = blockDim.x >> 6;
        for (int w = 0; w < nw; ++w) t += s_part[w];
        atomicAdd(out_loss, 0.5f * GAMMA * t);
    }
}

// ---------------------------------------------------------------------------
extern "C" void kernel_launch(void* const* d_in, const int* in_sizes, int n_in,
                              void* d_out, int out_size, void* d_ws, size_t ws_size,
                              hipStream_t stream) {
    const float* features     = (const float*)d_in[0];
    const float* W_enc        = (const float*)d_in[1];
    const float* b_enc        = (const float*)d_in[2];
    const float* W_p          = (const float*)d_in[3];
    const float* W_q          = (const float*)d_in[4];
    const float* b_u          = (const float*)d_in[5];
    const float* b_i          = (const float*)d_in[6];
    const float* vals         = (const float*)d_in[7];
    const int*   rows         = (const int*)d_in[8];
    const int*   cols         = (const int*)d_in[9];
    const int*   pos_idx      = (const int*)d_in[10];
    const int*   neg_item_idx = (const int*)d_in[11];

    const int num_users  = in_sizes[5];
    const int num_movies = in_sizes[6];
    const int in_feats   = in_sizes[0] / num_movies;   // 128
    const int nnz        = in_sizes[7];
    const int num_pos    = in_sizes[10];
    const int S          = in_sizes[11] / num_pos;     // 5

    // workspace layout (all fp32):
    //   P        : num_movies * 64
    //   Q        : num_movies * 64
    //   user_emb : num_users  * 64
    //   user_deg : num_users          (contiguous after user_emb for one memset)
    char* ws = (char*)d_ws;
    const size_t pq_bytes  = (size_t)num_movies * HIDDEN * sizeof(float);
    const size_t emb_bytes = (size_t)num_users * HIDDEN * sizeof(float);
    float* P        = (float*)(ws);
    float* Q        = (float*)(ws + pq_bytes);
    float* user_emb = (float*)(ws + 2 * pq_bytes);
    float* user_deg = (float*)(ws + 2 * pq_bytes + emb_bytes);

    float* out = (float*)d_out;

    // zero accumulators (every call: graph replays reuse buffers)
    hipMemsetAsync(out, 0, sizeof(float), stream);
    hipMemsetAsync(user_emb, 0, emb_bytes + (size_t)num_users * sizeof(float), stream);

    encode_kernel<<<640, 256, 0, stream>>>(features, W_enc, b_enc, W_p, W_q,
                                           P, Q, out, num_movies, in_feats);

    scatter_kernel<<<2048, 256, 0, stream>>>(vals, rows, cols, P,
                                             user_emb, user_deg, nnz);

    loss_kernel<<<(num_pos + 255) / 256, 256, 0, stream>>>(
        user_emb, user_deg, Q, b_u, b_i, rows, cols, pos_idx, neg_item_idx,
        num_pos, S, out);

    bias_reg_kernel<<<128, 256, 0, stream>>>(b_u, num_users, b_i, num_movies, out);
}

// Round 2
// 620.187 us; speedup vs baseline: 1.2809x; 1.2809x over previous
//
#include <hip/hip_runtime.h>

#define HIDDEN 64
#define BETA 0.01f
#define GAMMA 0.01f

// ---------------------------------------------------------------------------
// Kernel 1: fused encode + projections, one wave per movie row.
//   h = features[m] @ W_enc + b_enc          (128 -> 64)
//   P[m] = h @ W_p ; Q[m] = h @ W_q          (64 -> 64)
//   also accumulates 0.5*BETA*sum(P^2+Q^2) into out_loss.
// ---------------------------------------------------------------------------
__global__ void encode_kernel(const float* __restrict__ features,
                              const float* __restrict__ W_enc,
                              const float* __restrict__ b_enc,
                              const float* __restrict__ W_p,
                              const float* __restrict__ W_q,
                              float* __restrict__ P,
                              float* __restrict__ Q,
                              float* __restrict__ out_loss,
                              int num_movies, int in_feats) {
    const int lane  = threadIdx.x & 63;
    const int gwave = (blockIdx.x * blockDim.x + threadIdx.x) >> 6;
    const int nwaves = (gridDim.x * blockDim.x) >> 6;

    const float be = b_enc[lane];
    float reg = 0.0f;

    for (int m = gwave; m < num_movies; m += nwaves) {
        const float* frow = features + (size_t)m * in_feats;
        float h = be;
        for (int f = 0; f < in_feats; ++f) {
            h = fmaf(frow[f], W_enc[f * HIDDEN + lane], h);
        }
        float p = 0.0f, q = 0.0f;
        #pragma unroll 8
        for (int j = 0; j < HIDDEN; ++j) {
            float hj = __shfl(h, j);
            p = fmaf(hj, W_p[j * HIDDEN + lane], p);
            q = fmaf(hj, W_q[j * HIDDEN + lane], q);
        }
        P[(size_t)m * HIDDEN + lane] = p;
        Q[(size_t)m * HIDDEN + lane] = q;
        reg += p * p + q * q;
    }

    for (int off = 32; off; off >>= 1) reg += __shfl_down(reg, off);
    __shared__ float s_part[16];
    const int wave = threadIdx.x >> 6;
    if (lane == 0) s_part[wave] = reg;
    __syncthreads();
    if (threadIdx.x == 0) {
        float t = 0.0f;
        const int nw = blockDim.x >> 6;
        for (int w = 0; w < nw; ++w) t += s_part[w];
        atomicAdd(out_loss, 0.5f * BETA * t);
    }
}

// ---------------------------------------------------------------------------
// CSR build, step 1: histogram of rows.
// ---------------------------------------------------------------------------
__global__ void hist_kernel(const int* __restrict__ rows, int nnz,
                            int* __restrict__ counts) {
    const int tid = blockIdx.x * blockDim.x + threadIdx.x;
    const int stride = gridDim.x * blockDim.x;
    for (int e = tid; e < nnz; e += stride) {
        atomicAdd(&counts[rows[e]], 1);
    }
}

// ---------------------------------------------------------------------------
// CSR build, step 2a: per-block (256-element chunk) sums of counts.
// ---------------------------------------------------------------------------
__global__ void scan1_kernel(const int* __restrict__ counts, int n,
                             int* __restrict__ block_sums) {
    __shared__ int s[256];
    const int t = threadIdx.x;
    const int i = blockIdx.x * 256 + t;
    int x = (i < n) ? counts[i] : 0;
    s[t] = x;
    __syncthreads();
    for (int off = 128; off; off >>= 1) {
        if (t < off) s[t] += s[t + off];
        __syncthreads();
    }
    if (t == 0) block_sums[blockIdx.x] = s[0];
}

// ---------------------------------------------------------------------------
// CSR build, step 2b: single-block exclusive scan of block sums (nb <= 256).
// Thread 0 also writes row_start[n] = nnz.
// ---------------------------------------------------------------------------
__global__ void scan2_kernel(int* __restrict__ block_sums, int nb,
                             int* __restrict__ block_offsets,
                             int* __restrict__ row_start, int n, int nnz) {
    __shared__ int s[256];
    const int t = threadIdx.x;
    int x = (t < nb) ? block_sums[t] : 0;
    s[t] = x;
    __syncthreads();
    for (int off = 1; off < 256; off <<= 1) {
        int v = (t >= off) ? s[t - off] : 0;
        __syncthreads();
        s[t] += v;
        __syncthreads();
    }
    if (t < nb) block_offsets[t] = s[t] - x;   // exclusive
    if (t == 0) row_start[n] = nnz;
}

// ---------------------------------------------------------------------------
// CSR build, step 2c: per-chunk exclusive scan + chunk offset -> row_start.
// ---------------------------------------------------------------------------
__global__ void scan3_kernel(const int* __restrict__ counts, int n,
                             const int* __restrict__ block_offsets,
                             int* __restrict__ row_start) {
    __shared__ int s[256];
    const int t = threadIdx.x;
    const int i = blockIdx.x * 256 + t;
    int x = (i < n) ? counts[i] : 0;
    s[t] = x;
    __syncthreads();
    for (int off = 1; off < 256; off <<= 1) {
        int v = (t >= off) ? s[t - off] : 0;
        __syncthreads();
        s[t] += v;
        __syncthreads();
    }
    if (i < n) row_start[i] = block_offsets[blockIdx.x] + s[t] - x;
}

// ---------------------------------------------------------------------------
// CSR build, step 3: scatter (col, val) pairs into CSR slot order.
// ---------------------------------------------------------------------------
__global__ void fill_kernel(const int* __restrict__ rows,
                            const int* __restrict__ cols,
                            const float* __restrict__ vals, int nnz,
                            const int* __restrict__ row_start,
                            int* __restrict__ cursors,
                            uint2* __restrict__ pairs) {
    const int tid = blockIdx.x * blockDim.x + threadIdx.x;
    const int stride = gridDim.x * blockDim.x;
    for (int e = tid; e < nnz; e += stride) {
        const int r = rows[e];
        const int pos = atomicAdd(&cursors[r], 1);
        pairs[row_start[r] + pos] =
            make_uint2((unsigned)cols[e], __float_as_uint(vals[e]));
    }
}

// ---------------------------------------------------------------------------
// Segment sum, gather style: one wave per user, no atomics.
//   user_emb[u] = sum_s val_s * P[col_s] ; user_deg[u] = sum_s val_s
// ---------------------------------------------------------------------------
__global__ void gather_kernel(const int* __restrict__ row_start,
                              const uint2* __restrict__ pairs,
                              const float* __restrict__ P,
                              float* __restrict__ user_emb,
                              float* __restrict__ user_deg, int nu) {
    const int lane  = threadIdx.x & 63;
    const int gwave = (blockIdx.x * blockDim.x + threadIdx.x) >> 6;
    const int nwaves = (gridDim.x * blockDim.x) >> 6;

    for (int u = gwave; u < nu; u += nwaves) {
        const int s0 = row_start[u];
        const int s1 = row_start[u + 1];
        float acc = 0.0f, deg = 0.0f;
        for (int s = s0; s < s1; ++s) {
            const uint2 pr = pairs[s];
            const int   c = (int)pr.x;
            const float v = __uint_as_float(pr.y);
            acc = fmaf(v, P[(size_t)c * HIDDEN + lane], acc);
            deg += v;
        }
        user_emb[(size_t)u * HIDDEN + lane] = acc;
        if (lane == 0) user_deg[u] = deg;
    }
}

// ---------------------------------------------------------------------------
// Pair loss. One thread per positive pair.
// ---------------------------------------------------------------------------
__global__ void loss_kernel(const float* __restrict__ user_emb,
                            const float* __restrict__ user_deg,
                            const float* __restrict__ Q,
                            const float* __restrict__ b_u,
                            const float* __restrict__ b_i,
                            const int* __restrict__ rows,
                            const int* __restrict__ cols,
                            const int* __restrict__ pos_idx,
                            const int* __restrict__ neg_item_idx,
                            int num_pos, int S,
                            float* __restrict__ out_loss) {
    const int p = blockIdx.x * blockDim.x + threadIdx.x;
    float acc = 0.0f;

    if (p < num_pos) {
        const int e = pos_idx[p];
        const int u = rows[e];
        const int ii = cols[e];
        const float invdeg = 1.0f / user_deg[u];

        float ue[HIDDEN];
        const float4* uep = (const float4*)(user_emb + (size_t)u * HIDDEN);
        #pragma unroll
        for (int k = 0; k < HIDDEN / 4; ++k) {
            float4 t4 = uep[k];
            ue[4 * k + 0] = t4.x * invdeg;
            ue[4 * k + 1] = t4.y * invdeg;
            ue[4 * k + 2] = t4.z * invdeg;
            ue[4 * k + 3] = t4.w * invdeg;
        }
        const float bu = b_u[u];

        const float4* qp = (const float4*)(Q + (size_t)ii * HIDDEN);
        float dot = 0.0f;
        #pragma unroll
        for (int k = 0; k < HIDDEN / 4; ++k) {
            float4 t4 = qp[k];
            dot = fmaf(ue[4 * k + 0], t4.x, dot);
            dot = fmaf(ue[4 * k + 1], t4.y, dot);
            dot = fmaf(ue[4 * k + 2], t4.z, dot);
            dot = fmaf(ue[4 * k + 3], t4.w, dot);
        }
        const float r = bu + b_i[ii] + dot;

        for (int s = 0; s < S; ++s) {
            const int j = neg_item_idx[(size_t)p * S + s];
            const float4* qn = (const float4*)(Q + (size_t)j * HIDDEN);
            float dn = 0.0f;
            #pragma unroll
            for (int k = 0; k < HIDDEN / 4; ++k) {
                float4 t4 = qn[k];
                dn = fmaf(ue[4 * k + 0], t4.x, dn);
                dn = fmaf(ue[4 * k + 1], t4.y, dn);
                dn = fmaf(ue[4 * k + 2], t4.z, dn);
                dn = fmaf(ue[4 * k + 3], t4.w, dn);
            }
            const float nr = bu + b_i[j] + dn;
            const float diff = 1.0f - (r - nr);
            acc += 0.5f * diff * diff;
        }
    }

    for (int off = 32; off; off >>= 1) acc += __shfl_down(acc, off);
    __shared__ float s_part[16];
    const int wave = threadIdx.x >> 6;
    const int lane = threadIdx.x & 63;
    if (lane == 0) s_part[wave] = acc;
    __syncthreads();
    if (threadIdx.x == 0) {
        float t = 0.0f;
        const int nw = blockDim.x >> 6;
        for (int w = 0; w < nw; ++w) t += s_part[w];
        atomicAdd(out_loss, t);
    }
}

// ---------------------------------------------------------------------------
// Bias regularizer 0.5*GAMMA*(sum b_u^2 + sum b_i^2)
// ---------------------------------------------------------------------------
__global__ void bias_reg_kernel(const float* __restrict__ b_u, int nu,
                                const float* __restrict__ b_i, int ni,
                                float* __restrict__ out_loss) {
    const int tid = blockIdx.x * blockDim.x + threadIdx.x;
    const int stride = gridDim.x * blockDim.x;
    const int n = nu + ni;
    float acc = 0.0f;
    for (int x = tid; x < n; x += stride) {
        float v = (x < nu) ? b_u[x] : b_i[x - nu];
        acc += v * v;
    }
    for (int off = 32; off; off >>= 1) acc += __shfl_down(acc, off);
    __shared__ float s_part[16];
    const int wave = threadIdx.x >> 6;
    const int lane = threadIdx.x & 63;
    if (lane == 0) s_part[wave] = acc;
    __syncthreads();
    if (threadIdx.x == 0) {
        float t = 0.0f;
        const int nw = blockDim.x >> 6;
        for (int w = 0; w < nw; ++w) t += s_part[w];
        atomicAdd(out_loss, 0.5f * GAMMA * t);
    }
}

// ---------------------------------------------------------------------------
extern "C" void kernel_launch(void* const* d_in, const int* in_sizes, int n_in,
                              void* d_out, int out_size, void* d_ws, size_t ws_size,
                              hipStream_t stream) {
    const float* features     = (const float*)d_in[0];
    const float* W_enc        = (const float*)d_in[1];
    const float* b_enc        = (const float*)d_in[2];
    const float* W_p          = (const float*)d_in[3];
    const float* W_q          = (const float*)d_in[4];
    const float* b_u          = (const float*)d_in[5];
    const float* b_i          = (const float*)d_in[6];
    const float* vals         = (const float*)d_in[7];
    const int*   rows         = (const int*)d_in[8];
    const int*   cols         = (const int*)d_in[9];
    const int*   pos_idx      = (const int*)d_in[10];
    const int*   neg_item_idx = (const int*)d_in[11];

    const int num_users  = in_sizes[5];
    const int num_movies = in_sizes[6];
    const int in_feats   = in_sizes[0] / num_movies;   // 128
    const int nnz        = in_sizes[7];
    const int num_pos    = in_sizes[10];
    const int S          = in_sizes[11] / num_pos;     // 5

    const int nb = (num_users + 255) / 256;            // scan chunks (<=256 req)

    // workspace layout (256B-aligned segments)
    auto align256 = [](size_t x) { return (x + 255) & ~(size_t)255; };
    char* ws = (char*)d_ws;
    size_t off = 0;
    float* P         = (float*)(ws + off); off += align256((size_t)num_movies * HIDDEN * 4);
    float* Q         = (float*)(ws + off); off += align256((size_t)num_movies * HIDDEN * 4);
    float* user_emb  = (float*)(ws + off); off += align256((size_t)num_users * HIDDEN * 4);
    float* user_deg  = (float*)(ws + off); off += align256((size_t)num_users * 4);
    int*   counts    = (int*)(ws + off);   off += align256((size_t)num_users * 4);
    int*   cursors   = (int*)(ws + off);   off += align256((size_t)num_users * 4);
    int*   row_start = (int*)(ws + off);   off += align256((size_t)(num_users + 1) * 4);
    int*   block_sums    = (int*)(ws + off); off += align256(256 * 4);
    int*   block_offsets = (int*)(ws + off); off += align256(256 * 4);
    uint2* pairs     = (uint2*)(ws + off); off += align256((size_t)nnz * 8);

    float* out = (float*)d_out;

    // zero loss accumulator + counts + cursors (counts/cursors are adjacent)
    hipMemsetAsync(out, 0, sizeof(float), stream);
    hipMemsetAsync(counts, 0, align256((size_t)num_users * 4) + (size_t)num_users * 4, stream);

    encode_kernel<<<640, 256, 0, stream>>>(features, W_enc, b_enc, W_p, W_q,
                                           P, Q, out, num_movies, in_feats);

    hist_kernel<<<2048, 256, 0, stream>>>(rows, nnz, counts);
    scan1_kernel<<<nb, 256, 0, stream>>>(counts, num_users, block_sums);
    scan2_kernel<<<1, 256, 0, stream>>>(block_sums, nb, block_offsets,
                                        row_start, num_users, nnz);
    scan3_kernel<<<nb, 256, 0, stream>>>(counts, num_users, block_offsets, row_start);
    fill_kernel<<<2048, 256, 0, stream>>>(rows, cols, vals, nnz,
                                          row_start, cursors, pairs);
    gather_kernel<<<(num_users * 64 + 255) / 256, 256, 0, stream>>>(
        row_start, pairs, P, user_emb, user_deg, num_users);

    loss_kernel<<<(num_pos + 255) / 256, 256, 0, stream>>>(
        user_emb, user_deg, Q, b_u, b_i, rows, cols, pos_idx, neg_item_idx,
        num_pos, S, out);

    bias_reg_kernel<<<128, 256, 0, stream>>>(b_u, num_users, b_i, num_movies, out);
}

// Round 3
// 570.376 us; speedup vs baseline: 1.3927x; 1.0873x over previous
//
#include <hip/hip_runtime.h>

#define HIDDEN 64
#define BETA 0.01f
#define GAMMA 0.01f

// ---------------------------------------------------------------------------
// Encode phase A: H = features @ W_enc + b_enc   (thread per output element)
// frow reads are wave-uniform float4 broadcasts; W_enc columns are coalesced
// and L1-resident (32 KB). 4 accumulators for ILP.
// ---------------------------------------------------------------------------
__global__ void h_kernel(const float* __restrict__ features,
                         const float* __restrict__ W_enc,
                         const float* __restrict__ b_enc,
                         float* __restrict__ H,
                         int num_movies, int in_feats) {
    const int tid = blockIdx.x * blockDim.x + threadIdx.x;
    const int j = tid & 63;
    const int m = tid >> 6;
    if (m >= num_movies) return;

    const float* frow = features + (size_t)m * in_feats;
    float a0 = 0.0f, a1 = 0.0f, a2 = 0.0f, a3 = 0.0f;
    #pragma unroll 8
    for (int f = 0; f < in_feats; f += 4) {
        const float4 fv = *(const float4*)(frow + f);
        a0 = fmaf(fv.x, W_enc[(f + 0) * HIDDEN + j], a0);
        a1 = fmaf(fv.y, W_enc[(f + 1) * HIDDEN + j], a1);
        a2 = fmaf(fv.z, W_enc[(f + 2) * HIDDEN + j], a2);
        a3 = fmaf(fv.w, W_enc[(f + 3) * HIDDEN + j], a3);
    }
    H[(size_t)m * HIDDEN + j] = (a0 + a1) + (a2 + a3) + b_enc[j];
}

// ---------------------------------------------------------------------------
// Encode phase B: P = H @ W_p, Q = H @ W_q (thread per output element, both
// outputs share the H-row broadcast). Also accumulates 0.5*BETA*sum(P^2+Q^2).
// ---------------------------------------------------------------------------
__global__ void pq_kernel(const float* __restrict__ H,
                          const float* __restrict__ W_p,
                          const float* __restrict__ W_q,
                          float* __restrict__ P,
                          float* __restrict__ Q,
                          float* __restrict__ out_loss,
                          int num_movies) {
    const int tid = blockIdx.x * blockDim.x + threadIdx.x;
    const int j = tid & 63;
    const int m = tid >> 6;
    float reg = 0.0f;

    if (m < num_movies) {
        const float* hrow = H + (size_t)m * HIDDEN;
        float p0 = 0.0f, p1 = 0.0f, p2 = 0.0f, p3 = 0.0f;
        float q0 = 0.0f, q1 = 0.0f, q2 = 0.0f, q3 = 0.0f;
        #pragma unroll 4
        for (int f = 0; f < HIDDEN; f += 4) {
            const float4 hv = *(const float4*)(hrow + f);
            p0 = fmaf(hv.x, W_p[(f + 0) * HIDDEN + j], p0);
            p1 = fmaf(hv.y, W_p[(f + 1) * HIDDEN + j], p1);
            p2 = fmaf(hv.z, W_p[(f + 2) * HIDDEN + j], p2);
            p3 = fmaf(hv.w, W_p[(f + 3) * HIDDEN + j], p3);
            q0 = fmaf(hv.x, W_q[(f + 0) * HIDDEN + j], q0);
            q1 = fmaf(hv.y, W_q[(f + 1) * HIDDEN + j], q1);
            q2 = fmaf(hv.z, W_q[(f + 2) * HIDDEN + j], q2);
            q3 = fmaf(hv.w, W_q[(f + 3) * HIDDEN + j], q3);
        }
        const float p = (p0 + p1) + (p2 + p3);
        const float q = (q0 + q1) + (q2 + q3);
        P[(size_t)m * HIDDEN + j] = p;
        Q[(size_t)m * HIDDEN + j] = q;
        reg = p * p + q * q;
    }

    for (int off = 32; off; off >>= 1) reg += __shfl_down(reg, off);
    __shared__ float s_part[16];
    const int wave = threadIdx.x >> 6;
    const int lane = threadIdx.x & 63;
    if (lane == 0) s_part[wave] = reg;
    __syncthreads();
    if (threadIdx.x == 0) {
        float t = 0.0f;
        const int nw = blockDim.x >> 6;
        for (int w = 0; w < nw; ++w) t += s_part[w];
        atomicAdd(out_loss, 0.5f * BETA * t);
    }
}

// ---------------------------------------------------------------------------
// CSR build, step 1: histogram of rows.
// ---------------------------------------------------------------------------
__global__ void hist_kernel(const int* __restrict__ rows, int nnz,
                            int* __restrict__ counts) {
    const int tid = blockIdx.x * blockDim.x + threadIdx.x;
    const int stride = gridDim.x * blockDim.x;
    for (int e = tid; e < nnz; e += stride) {
        atomicAdd(&counts[rows[e]], 1);
    }
}

// ---------------------------------------------------------------------------
// CSR build, step 2a: per-chunk (256) sums of counts.
// ---------------------------------------------------------------------------
__global__ void scan1_kernel(const int* __restrict__ counts, int n,
                             int* __restrict__ block_sums) {
    __shared__ int s[256];
    const int t = threadIdx.x;
    const int i = blockIdx.x * 256 + t;
    int x = (i < n) ? counts[i] : 0;
    s[t] = x;
    __syncthreads();
    for (int off = 128; off; off >>= 1) {
        if (t < off) s[t] += s[t + off];
        __syncthreads();
    }
    if (t == 0) block_sums[blockIdx.x] = s[0];
}

// ---------------------------------------------------------------------------
// CSR build, step 2b: single-block exclusive scan of chunk sums (nb <= 256).
// ---------------------------------------------------------------------------
__global__ void scan2_kernel(int* __restrict__ block_sums, int nb,
                             int* __restrict__ block_offsets,
                             int* __restrict__ row_start, int n, int nnz) {
    __shared__ int s[256];
    const int t = threadIdx.x;
    int x = (t < nb) ? block_sums[t] : 0;
    s[t] = x;
    __syncthreads();
    for (int off = 1; off < 256; off <<= 1) {
        int v = (t >= off) ? s[t - off] : 0;
        __syncthreads();
        s[t] += v;
        __syncthreads();
    }
    if (t < nb) block_offsets[t] = s[t] - x;   // exclusive
    if (t == 0) row_start[n] = nnz;
}

// ---------------------------------------------------------------------------
// CSR build, step 2c: per-chunk exclusive scan -> row_start, and init cursors
// to row_start so fill's atomic yields absolute positions.
// ---------------------------------------------------------------------------
__global__ void scan3_kernel(const int* __restrict__ counts, int n,
                             const int* __restrict__ block_offsets,
                             int* __restrict__ row_start,
                             int* __restrict__ cursors) {
    __shared__ int s[256];
    const int t = threadIdx.x;
    const int i = blockIdx.x * 256 + t;
    int x = (i < n) ? counts[i] : 0;
    s[t] = x;
    __syncthreads();
    for (int off = 1; off < 256; off <<= 1) {
        int v = (t >= off) ? s[t - off] : 0;
        __syncthreads();
        s[t] += v;
        __syncthreads();
    }
    if (i < n) {
        const int rs = block_offsets[blockIdx.x] + s[t] - x;
        row_start[i] = rs;
        cursors[i] = rs;
    }
}

// ---------------------------------------------------------------------------
// CSR build, step 3: scatter (col, val) pairs into CSR slot order.
// cursors pre-initialized to row_start -> single atomic gives absolute slot.
// ---------------------------------------------------------------------------
__global__ void fill_kernel(const int* __restrict__ rows,
                            const int* __restrict__ cols,
                            const float* __restrict__ vals, int nnz,
                            int* __restrict__ cursors,
                            uint2* __restrict__ pairs) {
    const int tid = blockIdx.x * blockDim.x + threadIdx.x;
    const int stride = gridDim.x * blockDim.x;
    for (int e = tid; e < nnz; e += stride) {
        const int pos = atomicAdd(&cursors[rows[e]], 1);
        pairs[pos] = make_uint2((unsigned)cols[e], __float_as_uint(vals[e]));
    }
}

// ---------------------------------------------------------------------------
// Segment sum, gather style: one wave per user, no atomics, 2x unroll.
// ---------------------------------------------------------------------------
__global__ void gather_kernel(const int* __restrict__ row_start,
                              const uint2* __restrict__ pairs,
                              const float* __restrict__ P,
                              float* __restrict__ user_emb,
                              float* __restrict__ user_deg, int nu) {
    const int lane  = threadIdx.x & 63;
    const int gwave = (blockIdx.x * blockDim.x + threadIdx.x) >> 6;
    if (gwave >= nu) return;
    const int u = gwave;

    const int s0 = row_start[u];
    const int s1 = row_start[u + 1];
    float acc0 = 0.0f, acc1 = 0.0f, deg = 0.0f;
    int s = s0;
    for (; s + 1 < s1; s += 2) {
        const uint2 pr0 = pairs[s];
        const uint2 pr1 = pairs[s + 1];
        const float v0 = __uint_as_float(pr0.y);
        const float v1 = __uint_as_float(pr1.y);
        acc0 = fmaf(v0, P[(size_t)pr0.x * HIDDEN + lane], acc0);
        acc1 = fmaf(v1, P[(size_t)pr1.x * HIDDEN + lane], acc1);
        deg += v0 + v1;
    }
    if (s < s1) {
        const uint2 pr = pairs[s];
        const float v = __uint_as_float(pr.y);
        acc0 = fmaf(v, P[(size_t)pr.x * HIDDEN + lane], acc0);
        deg += v;
    }
    user_emb[(size_t)u * HIDDEN + lane] = acc0 + acc1;
    if (lane == 0) user_deg[u] = deg;
}

// ---------------------------------------------------------------------------
// Pair loss. One thread per positive pair.
// ---------------------------------------------------------------------------
__global__ void loss_kernel(const float* __restrict__ user_emb,
                            const float* __restrict__ user_deg,
                            const float* __restrict__ Q,
                            const float* __restrict__ b_u,
                            const float* __restrict__ b_i,
                            const int* __restrict__ rows,
                            const int* __restrict__ cols,
                            const int* __restrict__ pos_idx,
                            const int* __restrict__ neg_item_idx,
                            int num_pos, int S,
                            float* __restrict__ out_loss) {
    const int p = blockIdx.x * blockDim.x + threadIdx.x;
    float acc = 0.0f;

    if (p < num_pos) {
        const int e = pos_idx[p];
        const int u = rows[e];
        const int ii = cols[e];
        const float invdeg = 1.0f / user_deg[u];

        float ue[HIDDEN];
        const float4* uep = (const float4*)(user_emb + (size_t)u * HIDDEN);
        #pragma unroll
        for (int k = 0; k < HIDDEN / 4; ++k) {
            float4 t4 = uep[k];
            ue[4 * k + 0] = t4.x * invdeg;
            ue[4 * k + 1] = t4.y * invdeg;
            ue[4 * k + 2] = t4.z * invdeg;
            ue[4 * k + 3] = t4.w * invdeg;
        }
        const float bu = b_u[u];

        const float4* qp = (const float4*)(Q + (size_t)ii * HIDDEN);
        float dot = 0.0f;
        #pragma unroll
        for (int k = 0; k < HIDDEN / 4; ++k) {
            float4 t4 = qp[k];
            dot = fmaf(ue[4 * k + 0], t4.x, dot);
            dot = fmaf(ue[4 * k + 1], t4.y, dot);
            dot = fmaf(ue[4 * k + 2], t4.z, dot);
            dot = fmaf(ue[4 * k + 3], t4.w, dot);
        }
        const float r = bu + b_i[ii] + dot;

        for (int s = 0; s < S; ++s) {
            const int j = neg_item_idx[(size_t)p * S + s];
            const float4* qn = (const float4*)(Q + (size_t)j * HIDDEN);
            float dn = 0.0f;
            #pragma unroll
            for (int k = 0; k < HIDDEN / 4; ++k) {
                float4 t4 = qn[k];
                dn = fmaf(ue[4 * k + 0], t4.x, dn);
                dn = fmaf(ue[4 * k + 1], t4.y, dn);
                dn = fmaf(ue[4 * k + 2], t4.z, dn);
                dn = fmaf(ue[4 * k + 3], t4.w, dn);
            }
            const float nr = bu + b_i[j] + dn;
            const float diff = 1.0f - (r - nr);
            acc += 0.5f * diff * diff;
        }
    }

    for (int off = 32; off; off >>= 1) acc += __shfl_down(acc, off);
    __shared__ float s_part[16];
    const int wave = threadIdx.x >> 6;
    const int lane = threadIdx.x & 63;
    if (lane == 0) s_part[wave] = acc;
    __syncthreads();
    if (threadIdx.x == 0) {
        float t = 0.0f;
        const int nw = blockDim.x >> 6;
        for (int w = 0; w < nw; ++w) t += s_part[w];
        atomicAdd(out_loss, t);
    }
}

// ---------------------------------------------------------------------------
// Bias regularizer 0.5*GAMMA*(sum b_u^2 + sum b_i^2)
// ---------------------------------------------------------------------------
__global__ void bias_reg_kernel(const float* __restrict__ b_u, int nu,
                                const float* __restrict__ b_i, int ni,
                                float* __restrict__ out_loss) {
    const int tid = blockIdx.x * blockDim.x + threadIdx.x;
    const int stride = gridDim.x * blockDim.x;
    const int n = nu + ni;
    float acc = 0.0f;
    for (int x = tid; x < n; x += stride) {
        float v = (x < nu) ? b_u[x] : b_i[x - nu];
        acc += v * v;
    }
    for (int off = 32; off; off >>= 1) acc += __shfl_down(acc, off);
    __shared__ float s_part[16];
    const int wave = threadIdx.x >> 6;
    const int lane = threadIdx.x & 63;
    if (lane == 0) s_part[wave] = acc;
    __syncthreads();
    if (threadIdx.x == 0) {
        float t = 0.0f;
        const int nw = blockDim.x >> 6;
        for (int w = 0; w < nw; ++w) t += s_part[w];
        atomicAdd(out_loss, 0.5f * GAMMA * t);
    }
}

// ---------------------------------------------------------------------------
extern "C" void kernel_launch(void* const* d_in, const int* in_sizes, int n_in,
                              void* d_out, int out_size, void* d_ws, size_t ws_size,
                              hipStream_t stream) {
    const float* features     = (const float*)d_in[0];
    const float* W_enc        = (const float*)d_in[1];
    const float* b_enc        = (const float*)d_in[2];
    const float* W_p          = (const float*)d_in[3];
    const float* W_q          = (const float*)d_in[4];
    const float* b_u          = (const float*)d_in[5];
    const float* b_i          = (const float*)d_in[6];
    const float* vals         = (const float*)d_in[7];
    const int*   rows         = (const int*)d_in[8];
    const int*   cols         = (const int*)d_in[9];
    const int*   pos_idx      = (const int*)d_in[10];
    const int*   neg_item_idx = (const int*)d_in[11];

    const int num_users  = in_sizes[5];
    const int num_movies = in_sizes[6];
    const int in_feats   = in_sizes[0] / num_movies;   // 128
    const int nnz        = in_sizes[7];
    const int num_pos    = in_sizes[10];
    const int S          = in_sizes[11] / num_pos;     // 5

    const int nb = (num_users + 255) / 256;            // scan chunks (<=256 req)

    // workspace layout (256B-aligned segments)
    auto align256 = [](size_t x) { return (x + 255) & ~(size_t)255; };
    char* ws = (char*)d_ws;
    size_t off = 0;
    float* P         = (float*)(ws + off); off += align256((size_t)num_movies * HIDDEN * 4);
    float* Q         = (float*)(ws + off); off += align256((size_t)num_movies * HIDDEN * 4);
    float* H         = (float*)(ws + off); off += align256((size_t)num_movies * HIDDEN * 4);
    float* user_emb  = (float*)(ws + off); off += align256((size_t)num_users * HIDDEN * 4);
    float* user_deg  = (float*)(ws + off); off += align256((size_t)num_users * 4);
    int*   counts    = (int*)(ws + off);   off += align256((size_t)num_users * 4);
    int*   cursors   = (int*)(ws + off);   off += align256((size_t)num_users * 4);
    int*   row_start = (int*)(ws + off);   off += align256((size_t)(num_users + 1) * 4);
    int*   block_sums    = (int*)(ws + off); off += align256(256 * 4);
    int*   block_offsets = (int*)(ws + off); off += align256(256 * 4);
    uint2* pairs     = (uint2*)(ws + off); off += align256((size_t)nnz * 8);

    float* out = (float*)d_out;

    // zero loss accumulator + counts (cursors initialized by scan3)
    hipMemsetAsync(out, 0, sizeof(float), stream);
    hipMemsetAsync(counts, 0, (size_t)num_users * 4, stream);

    const int enc_blocks = (num_movies * 64 + 255) / 256;
    h_kernel<<<enc_blocks, 256, 0, stream>>>(features, W_enc, b_enc, H,
                                             num_movies, in_feats);
    pq_kernel<<<enc_blocks, 256, 0, stream>>>(H, W_p, W_q, P, Q, out, num_movies);

    hist_kernel<<<2048, 256, 0, stream>>>(rows, nnz, counts);
    scan1_kernel<<<nb, 256, 0, stream>>>(counts, num_users, block_sums);
    scan2_kernel<<<1, 256, 0, stream>>>(block_sums, nb, block_offsets,
                                        row_start, num_users, nnz);
    scan3_kernel<<<nb, 256, 0, stream>>>(counts, num_users, block_offsets,
                                         row_start, cursors);
    fill_kernel<<<2048, 256, 0, stream>>>(rows, cols, vals, nnz, cursors, pairs);

    gather_kernel<<<(num_users * 64 + 255) / 256, 256, 0, stream>>>(
        row_start, pairs, P, user_emb, user_deg, num_users);

    loss_kernel<<<(num_pos + 255) / 256, 256, 0, stream>>>(
        user_emb, user_deg, Q, b_u, b_i, rows, cols, pos_idx, neg_item_idx,
        num_pos, S, out);

    bias_reg_kernel<<<128, 256, 0, stream>>>(b_u, num_users, b_i, num_movies, out);
}